// Round 15
// baseline (1350.972 us; speedup 1.0000x reference)
//
#include <hip/hip_runtime.h>
#include <hip/hip_bf16.h>
#include <math.h>
#include <stdint.h>

#define D_MODEL 1024
#define D_STATE 128
#define D_INNER 2048
#define NCOLS   4352     // z(2048) + xm(2048) + B(128) + C(128); dt row handled separately
#define NB      4
#define TLEN    4096
#define BT      16384    // NB*TLEN
#define LCH     512      // chunk length
#define NCH     8        // TLEN/LCH

using bf16 = __hip_bfloat16;
typedef __attribute__((ext_vector_type(4))) float f32x4;
typedef __attribute__((ext_vector_type(8))) short short8x;

// fast clipped-silu: v_exp + v_rcp (~1e-7 rel).  Additive paths only.
__device__ __forceinline__ float csilu_fast(float v) {
    float e = __expf(-v);
    float s = v * __builtin_amdgcn_rcpf(1.f + e);
    return fminf(s, 8.f);
}

__device__ __forceinline__ void gload_lds16(const void* g, void* l) {
    __builtin_amdgcn_global_load_lds(
        (const __attribute__((address_space(1))) void*)g,
        (__attribute__((address_space(3))) void*)l, 16, 0, 0);
}

// ---------------- f32 -> bf16 cast ----------------
__global__ __launch_bounds__(256) void cast_kernel(const float* __restrict__ src,
                                                   bf16* __restrict__ dst, int n4) {
    int i = blockIdx.x * 256 + threadIdx.x;
    if (i < n4) {
        float4 v = ((const float4*)src)[i];
        dst[i*4+0] = __float2bfloat16(v.x);
        dst[i*4+1] = __float2bfloat16(v.y);
        dst[i*4+2] = __float2bfloat16(v.z);
        dst[i*4+3] = __float2bfloat16(v.w);
    }
}

// ---------------- f32 -> (hi, lo) bf16 split ----------------
__global__ __launch_bounds__(256) void split_kernel(const float* __restrict__ src,
                                                    bf16* __restrict__ hi,
                                                    bf16* __restrict__ lo, int n4) {
    int i = blockIdx.x * 256 + threadIdx.x;
    if (i < n4) {
        float4 v = ((const float4*)src)[i];
        #pragma unroll
        for (int j = 0; j < 4; ++j) {
            float f = (&v.x)[j];
            bf16 h = __float2bfloat16(f);
            hi[i*4+j] = h;
            lo[i*4+j] = __float2bfloat16(f - __bfloat162float(h));
        }
    }
}

// ---------------- GEMM1 split-bf16 MFMA: zxbcdt = x @ in_w^T ----------------
__global__ __launch_bounds__(256) void gemm1_split(const bf16* __restrict__ Ah,
                                                   const bf16* __restrict__ Al,
                                                   const bf16* __restrict__ Bh,
                                                   const bf16* __restrict__ Bl,
                                                   bf16* __restrict__ zdst,
                                                   float* __restrict__ xmdst,
                                                   float* __restrict__ bcdst) {
    const int K = D_MODEL;
    __shared__ __align__(16) bf16 sAh[128*32], sAl[128*32];
    __shared__ __align__(16) bf16 sBh[128*32], sBl[128*32];
    const int tid  = threadIdx.x;
    const int lane = tid & 63;
    const int wave = tid >> 6;
    const int wr   = (wave >> 1) * 64;
    const int wc   = (wave & 1) * 64;
    const long arow0 = (long)blockIdx.x * 128;
    const long brow0 = (long)blockIdx.y * 128;
    const long kb = (long)K * 2;
    const bool prec = (blockIdx.y >= 16);
    const char* gAh = (const char*)Ah;
    const char* gAl = (const char*)Al;
    const char* gBh = (const char*)Bh;
    const char* gBl = (const char*)Bl;

    f32x4 acc[4][4] = {};
    const int c1 = tid, c2 = tid + 256;
    const long aoff1 = (arow0 + (c1 >> 2)) * kb + (c1 & 3) * 16;
    const long aoff2 = (arow0 + (c2 >> 2)) * kb + (c2 & 3) * 16;
    const long boff1 = (brow0 + (c1 >> 2)) * kb + (c1 & 3) * 16;
    const long boff2 = (brow0 + (c2 >> 2)) * kb + (c2 & 3) * 16;

    for (int k0 = 0; k0 < K; k0 += 32) {
        __syncthreads();
        const long kk = (long)k0 * 2;
        gload_lds16(gAh + aoff1 + kk, (char*)sAh + c1*16);
        gload_lds16(gAh + aoff2 + kk, (char*)sAh + c2*16);
        gload_lds16(gBh + boff1 + kk, (char*)sBh + c1*16);
        gload_lds16(gBh + boff2 + kk, (char*)sBh + c2*16);
        if (prec) {
            gload_lds16(gAl + aoff1 + kk, (char*)sAl + c1*16);
            gload_lds16(gAl + aoff2 + kk, (char*)sAl + c2*16);
            gload_lds16(gBl + boff1 + kk, (char*)sBl + c1*16);
            gload_lds16(gBl + boff2 + kk, (char*)sBl + c2*16);
        }
        __syncthreads();

        const int r    = lane & 15;
        const int koff = (lane >> 4) * 8;
        short8x ah[4], bh[4];
        #pragma unroll
        for (int m = 0; m < 4; ++m)
            ah[m] = *(const short8x*)(sAh + (wr + m*16 + r) * 32 + koff);
        #pragma unroll
        for (int n = 0; n < 4; ++n)
            bh[n] = *(const short8x*)(sBh + (wc + n*16 + r) * 32 + koff);
        if (prec) {
            short8x al[4], bl[4];
            #pragma unroll
            for (int m = 0; m < 4; ++m)
                al[m] = *(const short8x*)(sAl + (wr + m*16 + r) * 32 + koff);
            #pragma unroll
            for (int n = 0; n < 4; ++n)
                bl[n] = *(const short8x*)(sBl + (wc + n*16 + r) * 32 + koff);
            #pragma unroll
            for (int m = 0; m < 4; ++m)
                #pragma unroll
                for (int n = 0; n < 4; ++n) {
                    acc[m][n] = __builtin_amdgcn_mfma_f32_16x16x32_bf16(ah[m], bh[n], acc[m][n], 0, 0, 0);
                    acc[m][n] = __builtin_amdgcn_mfma_f32_16x16x32_bf16(ah[m], bl[n], acc[m][n], 0, 0, 0);
                    acc[m][n] = __builtin_amdgcn_mfma_f32_16x16x32_bf16(al[m], bh[n], acc[m][n], 0, 0, 0);
                }
        } else {
            #pragma unroll
            for (int m = 0; m < 4; ++m)
                #pragma unroll
                for (int n = 0; n < 4; ++n)
                    acc[m][n] = __builtin_amdgcn_mfma_f32_16x16x32_bf16(ah[m], bh[n], acc[m][n], 0, 0, 0);
        }
    }

    const int r4 = (lane >> 4) * 4;
    const int cl = lane & 15;
    if (blockIdx.y < 16) {
        #pragma unroll
        for (int m = 0; m < 4; ++m)
            #pragma unroll
            for (int n = 0; n < 4; ++n) {
                const long row = arow0 + wr + m*16 + r4;
                const long col = brow0 + wc + n*16 + cl;
                #pragma unroll
                for (int j = 0; j < 4; ++j)
                    zdst[(row + j) * 2048 + col] = __float2bfloat16(acc[m][n][j]);
            }
    } else if (blockIdx.y < 32) {
        #pragma unroll
        for (int m = 0; m < 4; ++m)
            #pragma unroll
            for (int n = 0; n < 4; ++n) {
                const long row = arow0 + wr + m*16 + r4;
                const long col = brow0 - 2048 + wc + n*16 + cl;
                #pragma unroll
                for (int j = 0; j < 4; ++j)
                    xmdst[(row + j) * 2048 + col] = acc[m][n][j];
            }
    } else {
        #pragma unroll
        for (int m = 0; m < 4; ++m)
            #pragma unroll
            for (int n = 0; n < 4; ++n) {
                const long row = arow0 + wr + m*16 + r4;
                const long col = brow0 - 4096 + wc + n*16 + cl;
                #pragma unroll
                for (int j = 0; j < 4; ++j)
                    bcdst[(row + j) * 256 + col] = acc[m][n][j];
            }
    }
}

// ---------------- GEMM2 (m97 MFMA): out = ygated(bf16) @ w2b(bf16)^T ----------------
__global__ __launch_bounds__(256) void gemm2_mfma(const bf16* __restrict__ A,
                                                  const bf16* __restrict__ B,
                                                  float* __restrict__ C) {
    const int K = D_INNER;
    __shared__ __align__(16) bf16 sA[128*32];
    __shared__ __align__(16) bf16 sB[128*32];
    const int tid  = threadIdx.x;
    const int lane = tid & 63;
    const int wave = tid >> 6;
    const int wr   = (wave >> 1) * 64;
    const int wc   = (wave & 1) * 64;
    const long arow0 = (long)blockIdx.x * 128;
    const long brow0 = (long)blockIdx.y * 128;
    const long kb = (long)K * 2;
    const char* gA = (const char*)A;
    const char* gB = (const char*)B;

    f32x4 acc[4][4] = {};
    const int c1 = tid, c2 = tid + 256;
    for (int k0 = 0; k0 < K; k0 += 32) {
        __syncthreads();
        gload_lds16(gA + (arow0 + (c1 >> 2)) * kb + k0*2 + (c1 & 3) * 16, (char*)sA + c1*16);
        gload_lds16(gA + (arow0 + (c2 >> 2)) * kb + k0*2 + (c2 & 3) * 16, (char*)sA + c2*16);
        gload_lds16(gB + (brow0 + (c1 >> 2)) * kb + k0*2 + (c1 & 3) * 16, (char*)sB + c1*16);
        gload_lds16(gB + (brow0 + (c2 >> 2)) * kb + k0*2 + (c2 & 3) * 16, (char*)sB + c2*16);
        __syncthreads();

        const int r    = lane & 15;
        const int koff = (lane >> 4) * 8;
        short8x af[4], bfr[4];
        #pragma unroll
        for (int m = 0; m < 4; ++m)
            af[m] = *(const short8x*)(sA + (wr + m*16 + r) * 32 + koff);
        #pragma unroll
        for (int n = 0; n < 4; ++n)
            bfr[n] = *(const short8x*)(sB + (wc + n*16 + r) * 32 + koff);
        #pragma unroll
        for (int m = 0; m < 4; ++m)
            #pragma unroll
            for (int n = 0; n < 4; ++n)
                acc[m][n] = __builtin_amdgcn_mfma_f32_16x16x32_bf16(af[m], bfr[n], acc[m][n], 0, 0, 0);
    }

    const int r4 = (lane >> 4) * 4;
    const int cl = lane & 15;
    #pragma unroll
    for (int m = 0; m < 4; ++m) {
        #pragma unroll
        for (int n = 0; n < 4; ++n) {
            const long row = arow0 + wr + m*16 + r4;
            const long col = brow0 + wc + n*16 + cl;
            #pragma unroll
            for (int j = 0; j < 4; ++j)
                C[(row + j) * D_MODEL + col] = acc[m][n][j];
        }
    }
}

// ---------------- dt column in fp32 + softplus (accurate) ----------------
__global__ __launch_bounds__(256) void dt_gemv(const float* __restrict__ x,
                                               const float* __restrict__ wdt,
                                               float* __restrict__ dts) {
    const int row  = blockIdx.x * 4 + (threadIdx.x >> 6);
    const int lane = threadIdx.x & 63;
    const float4* xr = (const float4*)(x + (long)row * D_MODEL);
    const float4* wr = (const float4*)wdt;
    float acc = 0.f;
    for (int i = lane; i < D_MODEL/4; i += 64) {
        float4 a = xr[i], b = wr[i];
        acc += a.x*b.x + a.y*b.y + a.z*b.z + a.w*b.w;
    }
    for (int o = 32; o > 0; o >>= 1) acc += __shfl_down(acc, o);
    if (lane == 0)
        dts[row] = fmaxf(acc, 0.f) + log1pf(expf(-fabsf(acc)));
}

// ---------------- per-chunk (LCH=512) inclusive cumsum of dts ----------------
__global__ __launch_bounds__(LCH) void cumsum_chunks(const float* __restrict__ dts,
                                                     float* __restrict__ cumdt) {
    __shared__ float s[LCH];
    const int t = threadIdx.x;
    const long base = (long)blockIdx.x * LCH;
    s[t] = dts[base + t];
    __syncthreads();
    for (int o = 1; o < LCH; o <<= 1) {
        float v = (t >= o) ? s[t - o] : 0.f;
        __syncthreads();
        s[t] += v;
        __syncthreads();
    }
    cumdt[base + t] = s[t];
}

// ---------------- phase A: chunk-local scan + fused conv4, 8-way s-split ----------------
// Block = 512 threads = 8 waves; wave q owns states [16q,16q+16) for 64 channels.
// Decay exp staged in wave-private LDS slice (no barrier); B/C via wave-uniform
// scalar loads (readfirstlane'd base -> s_load into SGPRs); yred parity-buffered
// -> exactly 1 barrier per 8-row tile.  h[16]/thread keeps VGPR low for occupancy.
__global__ __launch_bounds__(512) void scan_local(const float* __restrict__ dts,
                                                  const float* __restrict__ bc,
                                                  const float* __restrict__ A_log,
                                                  const float* __restrict__ xm,
                                                  const float* __restrict__ cw,
                                                  const float* __restrict__ Dp,
                                                  bf16* __restrict__ ybuf,
                                                  float* __restrict__ hbuf) {
    const int tid = threadIdx.x;
    const int dl  = tid & 63;           // lane = channel slot
    const int q   = tid >> 6;           // wave id = s-octant (0..7)
    const int d   = blockIdx.x * 64 + dl;
    const int ch  = blockIdx.y;
    const int b   = blockIdx.z;
    const long row0 = (long)b * TLEN + ch * LCH;
    const int s0  = q * 16;
    const int s0u = __builtin_amdgcn_readfirstlane(s0);   // uniform for scalar loads

    // staging assignment: slot = dl + 64*i covers (r = slot>>4, sc = slot&15), i=0,1
    float Asv[2];
    #pragma unroll
    for (int i = 0; i < 2; ++i)
        Asv[i] = -expf(A_log[s0 + ((dl + 64*i) & 15)]);

    const float w0 = cw[d*4+0], w1 = cw[d*4+1], w2 = cw[d*4+2], w3 = cw[d*4+3];
    const float dpv = Dp[d];

    float p0 = 0.f, p1 = 0.f, p2 = 0.f;
    if (ch != 0) {
        p0 = csilu_fast(xm[(row0 - 3) * 2048 + d]);
        p1 = csilu_fast(xm[(row0 - 2) * 2048 + d]);
        p2 = csilu_fast(xm[(row0 - 1) * 2048 + d]);
    }

    float h[16];
    #pragma unroll
    for (int k = 0; k < 16; ++k) h[k] = 0.f;

    __shared__ __align__(16) float sa[8][128];          //  4 KB, wave-private 16-col slices
    __shared__ __align__(16) float yred[2][8][8][64];   // 32 KB, parity-buffered
    int pbuf = 0;

    for (int tt = 0; tt < LCH; tt += 8) {
        // per-wave staging of the decay factors (wave-private columns -> no barrier)
        #pragma unroll
        for (int i = 0; i < 2; ++i) {
            const int slot = dl + 64*i;
            const int r  = slot >> 4;            // 0..7
            const int sc = slot & 15;
            sa[r][s0 + sc] = __expf(Asv[i] * dts[row0 + tt + r]);
        }
        #pragma unroll
        for (int r = 0; r < 8; ++r) {
            const long row = row0 + tt + r;
            const float dtrow = dts[row];                       // uniform scalar
            const float* __restrict__ pB = bc + row * 256 + s0u;   // uniform base
            const float* __restrict__ pC = pB + 128;
            const float cur = csilu_fast(xm[row * 2048 + d]);
            const float xc  = csilu_fast(w0*p0 + w1*p1 + w2*p2 + w3*cur);
            p0 = p1; p1 = p2; p2 = cur;
            const float dtxc = dtrow * xc;
            float y0 = 0.f, y1 = 0.f, y2 = 0.f, y3 = 0.f;
            #pragma unroll
            for (int k = 0; k < 4; ++k) {
                const float4 a4 = *(const float4*)&sa[r][s0 + k*4];
                h[k*4+0] = fmaf(a4.x, h[k*4+0], pB[k*4+0] * dtxc);
                h[k*4+1] = fmaf(a4.y, h[k*4+1], pB[k*4+1] * dtxc);
                h[k*4+2] = fmaf(a4.z, h[k*4+2], pB[k*4+2] * dtxc);
                h[k*4+3] = fmaf(a4.w, h[k*4+3], pB[k*4+3] * dtxc);
                y0 = fmaf(h[k*4+0], pC[k*4+0], y0);
                y1 = fmaf(h[k*4+1], pC[k*4+1], y1);
                y2 = fmaf(h[k*4+2], pC[k*4+2], y2);
                y3 = fmaf(h[k*4+3], pC[k*4+3], y3);
            }
            yred[pbuf][r][q][dl] = (y0 + y1) + (y2 + y3) + (q == 0 ? dpv * xc : 0.f);
        }
        __syncthreads();                         // yred[pbuf] visible to all waves
        {
            const int r = tid >> 6, dl2 = tid & 63;   // 512 threads <-> 8 rows x 64 ch
            float y = 0.f;
            #pragma unroll
            for (int q2 = 0; q2 < 8; ++q2) y += yred[pbuf][r][q2][dl2];
            ybuf[(row0 + tt + r) * 2048 + blockIdx.x * 64 + dl2] = __float2bfloat16(y);
        }
        pbuf ^= 1;                               // next tile writes other parity
    }
    // chunk-final h, transposed layout [d][s]: 16 contiguous floats per thread
    const long hb = ((long)(b * NCH + ch) * 2048 + d) * 128 + s0;
    #pragma unroll
    for (int k = 0; k < 4; ++k)
        *(float4*)&hbuf[hb + k*4] = make_float4(h[k*4], h[k*4+1], h[k*4+2], h[k*4+3]);
}

// ---------------- phase B: cross-chunk combine; h_in -> hi/lo bf16 (transposed) + hT ----------------
__global__ __launch_bounds__(256) void scan_comb(const float* __restrict__ hbuf,
                                                 const float* __restrict__ cumdt,
                                                 const float* __restrict__ A_log,
                                                 bf16* __restrict__ hinH,
                                                 bf16* __restrict__ hinL,
                                                 float* __restrict__ hT) {
    const long idx = (long)blockIdx.x * 256 + threadIdx.x;   // over B*D*S, s fastest
    const int s = (int)(idx & 127);
    const int d = (int)((idx >> 7) & 2047);
    const int b = (int)(idx >> 18);
    const float As = -expf(A_log[s]);
    float hr = 0.f;
    for (int c = 0; c < NCH; ++c) {
        const long off = ((long)(b * NCH + c) * 2048 + d) * 128 + s;
        const float loc = hbuf[off];
        const bf16 hh = __float2bfloat16(hr);
        hinH[off] = hh;
        hinL[off] = __float2bfloat16(hr - __bfloat162float(hh));
        const float p = __expf(As * cumdt[(long)b * TLEN + c * LCH + (LCH - 1)]);
        hr = p * hr + loc;
    }
    hT[((long)b * 2048 + d) * 128 + s] = hr;
}

// ---------------- phase C as GEMM: Y += Cmod(512x128) @ Hin(128x2048) per (b,ch) ----------------
__global__ __launch_bounds__(256) void corr_gemm(const float* __restrict__ cumdt,
                                                 const float* __restrict__ bc,
                                                 const float* __restrict__ A_log,
                                                 const bf16* __restrict__ hinH,
                                                 const bf16* __restrict__ hinL,
                                                 bf16* __restrict__ ybuf) {
    __shared__ __align__(16) bf16 sA[128*32];
    __shared__ __align__(16) bf16 sBh[128*32], sBl[128*32];
    const int tid  = threadIdx.x;
    const int lane = tid & 63;
    const int wave = tid >> 6;
    const int wr   = (wave >> 1) * 64;
    const int wc   = (wave & 1) * 64;
    const long arow0 = (long)blockIdx.x * 128;      // rows over BT (within one 512-chunk)
    const long bcol0 = (long)blockIdx.y * 128;      // channels
    const int b  = (int)(arow0 >> 12);
    const int ch = (int)((arow0 & 4095) >> 9);
    const char* gH = (const char*)(hinH + (long)(b * NCH + ch) * 2048 * 128);
    const char* gL = (const char*)(hinL + (long)(b * NCH + ch) * 2048 * 128);

    f32x4 acc[4][4] = {};
    const int c1 = tid, c2 = tid + 256;
    for (int k0 = 0; k0 < 128; k0 += 32) {
        __syncthreads();
        {
            const int r   = tid >> 1;
            const int kk0 = (tid & 1) * 16;
            const long row = arow0 + r;
            const float cd = cumdt[row];
            #pragma unroll
            for (int t2 = 0; t2 < 16; ++t2) {
                const int s = k0 + kk0 + t2;
                const float As = -__expf(A_log[s]);
                const float cm = bc[row*256 + 128 + s] * __expf(As * cd);
                sA[r*32 + kk0 + t2] = __float2bfloat16(cm);
            }
        }
        gload_lds16(gH + (bcol0 + (c1 >> 2))*256 + k0*2 + (c1 & 3)*16, (char*)sBh + c1*16);
        gload_lds16(gH + (bcol0 + (c2 >> 2))*256 + k0*2 + (c2 & 3)*16, (char*)sBh + c2*16);
        gload_lds16(gL + (bcol0 + (c1 >> 2))*256 + k0*2 + (c1 & 3)*16, (char*)sBl + c1*16);
        gload_lds16(gL + (bcol0 + (c2 >> 2))*256 + k0*2 + (c2 & 3)*16, (char*)sBl + c2*16);
        __syncthreads();

        const int r    = lane & 15;
        const int koff = (lane >> 4) * 8;
        short8x af[4], bh[4], bl[4];
        #pragma unroll
        for (int m = 0; m < 4; ++m)
            af[m] = *(const short8x*)(sA + (wr + m*16 + r) * 32 + koff);
        #pragma unroll
        for (int n = 0; n < 4; ++n) {
            bh[n] = *(const short8x*)(sBh + (wc + n*16 + r) * 32 + koff);
            bl[n] = *(const short8x*)(sBl + (wc + n*16 + r) * 32 + koff);
        }
        #pragma unroll
        for (int m = 0; m < 4; ++m)
            #pragma unroll
            for (int n = 0; n < 4; ++n) {
                acc[m][n] = __builtin_amdgcn_mfma_f32_16x16x32_bf16(af[m], bh[n], acc[m][n], 0, 0, 0);
                acc[m][n] = __builtin_amdgcn_mfma_f32_16x16x32_bf16(af[m], bl[n], acc[m][n], 0, 0, 0);
            }
    }

    const int r4 = (lane >> 4) * 4;
    const int cl = lane & 15;
    #pragma unroll
    for (int m = 0; m < 4; ++m) {
        #pragma unroll
        for (int n = 0; n < 4; ++n) {
            const long row = arow0 + wr + m*16 + r4;
            const long col = bcol0 + wc + n*16 + cl;
            #pragma unroll
            for (int j = 0; j < 4; ++j) {
                const long o = (row + j) * 2048 + col;
                ybuf[o] = __float2bfloat16(__bfloat162float(ybuf[o]) + acc[m][n][j]);
            }
        }
    }
}

// ---------------- RMSNorm * norm_w * csilu(z): ygated bf16 written over z ----------------
__global__ __launch_bounds__(256) void rms_z(const bf16* __restrict__ ybuf,
                                             bf16* __restrict__ zg,
                                             const float* __restrict__ norm_w) {
    const long row = blockIdx.x;
    const int tid = threadIdx.x;
    float v[8];
    float ss = 0.f;
    #pragma unroll
    for (int i = 0; i < 8; ++i) {
        v[i] = __bfloat162float(ybuf[row * D_INNER + i*256 + tid]);
        ss += v[i] * v[i];
    }
    __shared__ float red[256];
    red[tid] = ss;
    __syncthreads();
    for (int o = 128; o > 0; o >>= 1) {
        if (tid < o) red[tid] += red[tid + o];
        __syncthreads();
    }
    const float scale = rsqrtf(red[0] * (1.f / D_INNER) + 1e-5f);
    #pragma unroll
    for (int i = 0; i < 8; ++i) {
        const int dd = i*256 + tid;
        const float z = __bfloat162float(zg[row * D_INNER + dd]);
        zg[row * D_INNER + dd] = __float2bfloat16(v[i] * scale * norm_w[dd] * csilu_fast(z));
    }
}

extern "C" void kernel_launch(void* const* d_in, const int* in_sizes, int n_in,
                              void* d_out, int out_size, void* d_ws, size_t ws_size,
                              hipStream_t stream) {
    const float* x      = (const float*)d_in[0];
    const float* in_w   = (const float*)d_in[1];   // (4353, 1024)
    const float* conv_w = (const float*)d_in[2];   // (2048, 1, 4)
    const float* A_log  = (const float*)d_in[3];   // (128,)
    const float* Dp     = (const float*)d_in[4];   // (2048,)
    const float* norm_w = (const float*)d_in[5];   // (2048,)
    const float* out_w  = (const float*)d_in[6];   // (1024, 2048)
    float* out = (float*)d_out;
    float* hT  = out + (long)BT * D_MODEL;

    char* ws = (char*)d_ws;
    size_t off = 0;
    auto alloc = [&](size_t bytes) { void* p = ws + off; off += (bytes + 255) & ~(size_t)255; return p; };
    bf16*  zg    = (bf16*) alloc((size_t)BT * D_INNER * 2);               //  67.1 MB: z -> ygated
    float* xm    = (float*)alloc((size_t)BT * D_INNER * 4);               // 134.2 MB: xm f32
    float* bcbuf = (float*)alloc((size_t)BT * 256 * 4);                   //  16.8 MB: B|C f32
    bf16*  w2b   = (bf16*) alloc((size_t)D_MODEL * D_INNER * 2);          //   4.2 MB
    float* hbuf  = (float*)alloc((size_t)NB * NCH * 128 * D_INNER * 4);   //  33.5 MB
    float* dts   = (float*)alloc((size_t)BT * 4);
    float* cumdt = (float*)alloc((size_t)BT * 4);
    // total ~256.0 MB (PROVEN).  Guarded.
    if (ws_size < off) return;

    // Aliases (lifetime-disjoint):
    bf16* whi = (bf16*)hbuf;                      // [split_w -> gemm1]; hbuf written by scan_local
    bf16* wlo = whi + (size_t)NCOLS * D_MODEL;
    bf16* xhi = (bf16*)d_out;                     // [split_x -> gemm1]
    bf16* xlo = xhi + (size_t)BT * D_MODEL;
    bf16* ybuf = (bf16*)d_out;                    // [scan_local -> rms_z], then gemm2 writes out
    bf16* hinH = (bf16*)xm;                       // [comb -> corr]; xm dead after scan_local
    bf16* hinL = hinH + (size_t)NB * NCH * D_INNER * 128;

    split_kernel<<<BT*D_MODEL/4/256, 256, 0, stream>>>(x, xhi, xlo, BT*D_MODEL/4);
    split_kernel<<<NCOLS*D_MODEL/4/256, 256, 0, stream>>>(in_w, whi, wlo, NCOLS*D_MODEL/4);
    cast_kernel<<<D_MODEL*D_INNER/4/256, 256, 0, stream>>>(out_w, w2b, D_MODEL*D_INNER/4);

    gemm1_split<<<dim3(BT/128, NCOLS/128), 256, 0, stream>>>(xhi, xlo, whi, wlo, zg, xm, bcbuf);
    dt_gemv<<<BT/4, 256, 0, stream>>>(x, in_w + (long)NCOLS * D_MODEL, dts);
    cumsum_chunks<<<NB*NCH, LCH, 0, stream>>>(dts, cumdt);
    scan_local<<<dim3(D_INNER/64, NCH, NB), 512, 0, stream>>>(dts, bcbuf, A_log, xm, conv_w, Dp, ybuf, hbuf);
    scan_comb<<<NB*128*D_INNER/256, 256, 0, stream>>>(hbuf, cumdt, A_log, hinH, hinL, hT);
    corr_gemm<<<dim3(BT/128, D_INNER/128), 256, 0, stream>>>(cumdt, bcbuf, A_log, hinH, hinL, ybuf);
    rms_z<<<BT, 256, 0, stream>>>(ybuf, zg, norm_w);
    gemm2_mfma<<<dim3(BT/128, D_MODEL/128), 256, 0, stream>>>(zg, w2b, out);
}

// Round 16
// 1266.496 us; speedup vs baseline: 1.0667x; 1.0667x over previous
//
#include <hip/hip_runtime.h>
#include <hip/hip_bf16.h>
#include <math.h>
#include <stdint.h>

#define D_MODEL 1024
#define D_STATE 128
#define D_INNER 2048
#define NCOLS   4352     // z(2048) + xm(2048) + B(128) + C(128); dt row handled separately
#define NB      4
#define TLEN    4096
#define BT      16384    // NB*TLEN
#define LCH     512      // chunk length
#define NCH     8        // TLEN/LCH

using bf16 = __hip_bfloat16;
typedef __attribute__((ext_vector_type(2))) float f32x2;
typedef __attribute__((ext_vector_type(4))) float f32x4;
typedef __attribute__((ext_vector_type(8))) short short8x;

// fast clipped-silu: v_exp + v_rcp (~1e-7 rel).  Additive paths only.
__device__ __forceinline__ float csilu_fast(float v) {
    float e = __expf(-v);
    float s = v * __builtin_amdgcn_rcpf(1.f + e);
    return fminf(s, 8.f);
}

__device__ __forceinline__ void gload_lds16(const void* g, void* l) {
    __builtin_amdgcn_global_load_lds(
        (const __attribute__((address_space(1))) void*)g,
        (__attribute__((address_space(3))) void*)l, 16, 0, 0);
}

// ---------------- f32 -> bf16 cast ----------------
__global__ __launch_bounds__(256) void cast_kernel(const float* __restrict__ src,
                                                   bf16* __restrict__ dst, int n4) {
    int i = blockIdx.x * 256 + threadIdx.x;
    if (i < n4) {
        float4 v = ((const float4*)src)[i];
        dst[i*4+0] = __float2bfloat16(v.x);
        dst[i*4+1] = __float2bfloat16(v.y);
        dst[i*4+2] = __float2bfloat16(v.z);
        dst[i*4+3] = __float2bfloat16(v.w);
    }
}

// ---------------- f32 -> (hi, lo) bf16 split ----------------
__global__ __launch_bounds__(256) void split_kernel(const float* __restrict__ src,
                                                    bf16* __restrict__ hi,
                                                    bf16* __restrict__ lo, int n4) {
    int i = blockIdx.x * 256 + threadIdx.x;
    if (i < n4) {
        float4 v = ((const float4*)src)[i];
        #pragma unroll
        for (int j = 0; j < 4; ++j) {
            float f = (&v.x)[j];
            bf16 h = __float2bfloat16(f);
            hi[i*4+j] = h;
            lo[i*4+j] = __float2bfloat16(f - __bfloat162float(h));
        }
    }
}

// ---------------- GEMM1 split-bf16 MFMA: zxbcdt = x @ in_w^T ----------------
__global__ __launch_bounds__(256) void gemm1_split(const bf16* __restrict__ Ah,
                                                   const bf16* __restrict__ Al,
                                                   const bf16* __restrict__ Bh,
                                                   const bf16* __restrict__ Bl,
                                                   bf16* __restrict__ zdst,
                                                   float* __restrict__ xmdst,
                                                   float* __restrict__ bcdst) {
    const int K = D_MODEL;
    __shared__ __align__(16) bf16 sAh[128*32], sAl[128*32];
    __shared__ __align__(16) bf16 sBh[128*32], sBl[128*32];
    const int tid  = threadIdx.x;
    const int lane = tid & 63;
    const int wave = tid >> 6;
    const int wr   = (wave >> 1) * 64;
    const int wc   = (wave & 1) * 64;
    const long arow0 = (long)blockIdx.x * 128;
    const long brow0 = (long)blockIdx.y * 128;
    const long kb = (long)K * 2;
    const bool prec = (blockIdx.y >= 16);
    const char* gAh = (const char*)Ah;
    const char* gAl = (const char*)Al;
    const char* gBh = (const char*)Bh;
    const char* gBl = (const char*)Bl;

    f32x4 acc[4][4] = {};
    const int c1 = tid, c2 = tid + 256;
    const long aoff1 = (arow0 + (c1 >> 2)) * kb + (c1 & 3) * 16;
    const long aoff2 = (arow0 + (c2 >> 2)) * kb + (c2 & 3) * 16;
    const long boff1 = (brow0 + (c1 >> 2)) * kb + (c1 & 3) * 16;
    const long boff2 = (brow0 + (c2 >> 2)) * kb + (c2 & 3) * 16;

    for (int k0 = 0; k0 < K; k0 += 32) {
        __syncthreads();
        const long kk = (long)k0 * 2;
        gload_lds16(gAh + aoff1 + kk, (char*)sAh + c1*16);
        gload_lds16(gAh + aoff2 + kk, (char*)sAh + c2*16);
        gload_lds16(gBh + boff1 + kk, (char*)sBh + c1*16);
        gload_lds16(gBh + boff2 + kk, (char*)sBh + c2*16);
        if (prec) {
            gload_lds16(gAl + aoff1 + kk, (char*)sAl + c1*16);
            gload_lds16(gAl + aoff2 + kk, (char*)sAl + c2*16);
            gload_lds16(gBl + boff1 + kk, (char*)sBl + c1*16);
            gload_lds16(gBl + boff2 + kk, (char*)sBl + c2*16);
        }
        __syncthreads();

        const int r    = lane & 15;
        const int koff = (lane >> 4) * 8;
        short8x ah[4], bh[4];
        #pragma unroll
        for (int m = 0; m < 4; ++m)
            ah[m] = *(const short8x*)(sAh + (wr + m*16 + r) * 32 + koff);
        #pragma unroll
        for (int n = 0; n < 4; ++n)
            bh[n] = *(const short8x*)(sBh + (wc + n*16 + r) * 32 + koff);
        if (prec) {
            short8x al[4], bl[4];
            #pragma unroll
            for (int m = 0; m < 4; ++m)
                al[m] = *(const short8x*)(sAl + (wr + m*16 + r) * 32 + koff);
            #pragma unroll
            for (int n = 0; n < 4; ++n)
                bl[n] = *(const short8x*)(sBl + (wc + n*16 + r) * 32 + koff);
            #pragma unroll
            for (int m = 0; m < 4; ++m)
                #pragma unroll
                for (int n = 0; n < 4; ++n) {
                    acc[m][n] = __builtin_amdgcn_mfma_f32_16x16x32_bf16(ah[m], bh[n], acc[m][n], 0, 0, 0);
                    acc[m][n] = __builtin_amdgcn_mfma_f32_16x16x32_bf16(ah[m], bl[n], acc[m][n], 0, 0, 0);
                    acc[m][n] = __builtin_amdgcn_mfma_f32_16x16x32_bf16(al[m], bh[n], acc[m][n], 0, 0, 0);
                }
        } else {
            #pragma unroll
            for (int m = 0; m < 4; ++m)
                #pragma unroll
                for (int n = 0; n < 4; ++n)
                    acc[m][n] = __builtin_amdgcn_mfma_f32_16x16x32_bf16(ah[m], bh[n], acc[m][n], 0, 0, 0);
        }
    }

    const int r4 = (lane >> 4) * 4;
    const int cl = lane & 15;
    if (blockIdx.y < 16) {
        #pragma unroll
        for (int m = 0; m < 4; ++m)
            #pragma unroll
            for (int n = 0; n < 4; ++n) {
                const long row = arow0 + wr + m*16 + r4;
                const long col = brow0 + wc + n*16 + cl;
                #pragma unroll
                for (int j = 0; j < 4; ++j)
                    zdst[(row + j) * 2048 + col] = __float2bfloat16(acc[m][n][j]);
            }
    } else if (blockIdx.y < 32) {
        #pragma unroll
        for (int m = 0; m < 4; ++m)
            #pragma unroll
            for (int n = 0; n < 4; ++n) {
                const long row = arow0 + wr + m*16 + r4;
                const long col = brow0 - 2048 + wc + n*16 + cl;
                #pragma unroll
                for (int j = 0; j < 4; ++j)
                    xmdst[(row + j) * 2048 + col] = acc[m][n][j];
            }
    } else {
        #pragma unroll
        for (int m = 0; m < 4; ++m)
            #pragma unroll
            for (int n = 0; n < 4; ++n) {
                const long row = arow0 + wr + m*16 + r4;
                const long col = brow0 - 4096 + wc + n*16 + cl;
                #pragma unroll
                for (int j = 0; j < 4; ++j)
                    bcdst[(row + j) * 256 + col] = acc[m][n][j];
            }
    }
}

// ---------------- GEMM2 (m97 MFMA): out = ygated(bf16) @ w2b(bf16)^T ----------------
__global__ __launch_bounds__(256) void gemm2_mfma(const bf16* __restrict__ A,
                                                  const bf16* __restrict__ B,
                                                  float* __restrict__ C) {
    const int K = D_INNER;
    __shared__ __align__(16) bf16 sA[128*32];
    __shared__ __align__(16) bf16 sB[128*32];
    const int tid  = threadIdx.x;
    const int lane = tid & 63;
    const int wave = tid >> 6;
    const int wr   = (wave >> 1) * 64;
    const int wc   = (wave & 1) * 64;
    const long arow0 = (long)blockIdx.x * 128;
    const long brow0 = (long)blockIdx.y * 128;
    const long kb = (long)K * 2;
    const char* gA = (const char*)A;
    const char* gB = (const char*)B;

    f32x4 acc[4][4] = {};
    const int c1 = tid, c2 = tid + 256;
    for (int k0 = 0; k0 < K; k0 += 32) {
        __syncthreads();
        gload_lds16(gA + (arow0 + (c1 >> 2)) * kb + k0*2 + (c1 & 3) * 16, (char*)sA + c1*16);
        gload_lds16(gA + (arow0 + (c2 >> 2)) * kb + k0*2 + (c2 & 3) * 16, (char*)sA + c2*16);
        gload_lds16(gB + (brow0 + (c1 >> 2)) * kb + k0*2 + (c1 & 3) * 16, (char*)sB + c1*16);
        gload_lds16(gB + (brow0 + (c2 >> 2)) * kb + k0*2 + (c2 & 3) * 16, (char*)sB + c2*16);
        __syncthreads();

        const int r    = lane & 15;
        const int koff = (lane >> 4) * 8;
        short8x af[4], bfr[4];
        #pragma unroll
        for (int m = 0; m < 4; ++m)
            af[m] = *(const short8x*)(sA + (wr + m*16 + r) * 32 + koff);
        #pragma unroll
        for (int n = 0; n < 4; ++n)
            bfr[n] = *(const short8x*)(sB + (wc + n*16 + r) * 32 + koff);
        #pragma unroll
        for (int m = 0; m < 4; ++m)
            #pragma unroll
            for (int n = 0; n < 4; ++n)
                acc[m][n] = __builtin_amdgcn_mfma_f32_16x16x32_bf16(af[m], bfr[n], acc[m][n], 0, 0, 0);
    }

    const int r4 = (lane >> 4) * 4;
    const int cl = lane & 15;
    #pragma unroll
    for (int m = 0; m < 4; ++m) {
        #pragma unroll
        for (int n = 0; n < 4; ++n) {
            const long row = arow0 + wr + m*16 + r4;
            const long col = brow0 + wc + n*16 + cl;
            #pragma unroll
            for (int j = 0; j < 4; ++j)
                C[(row + j) * D_MODEL + col] = acc[m][n][j];
        }
    }
}

// ---------------- dt column in fp32 + softplus (accurate) ----------------
__global__ __launch_bounds__(256) void dt_gemv(const float* __restrict__ x,
                                               const float* __restrict__ wdt,
                                               float* __restrict__ dts) {
    const int row  = blockIdx.x * 4 + (threadIdx.x >> 6);
    const int lane = threadIdx.x & 63;
    const float4* xr = (const float4*)(x + (long)row * D_MODEL);
    const float4* wr = (const float4*)wdt;
    float acc = 0.f;
    for (int i = lane; i < D_MODEL/4; i += 64) {
        float4 a = xr[i], b = wr[i];
        acc += a.x*b.x + a.y*b.y + a.z*b.z + a.w*b.w;
    }
    for (int o = 32; o > 0; o >>= 1) acc += __shfl_down(acc, o);
    if (lane == 0)
        dts[row] = fmaxf(acc, 0.f) + log1pf(expf(-fabsf(acc)));
}

// ---------------- per-chunk (LCH=512) inclusive cumsum of dts ----------------
__global__ __launch_bounds__(LCH) void cumsum_chunks(const float* __restrict__ dts,
                                                     float* __restrict__ cumdt) {
    __shared__ float s[LCH];
    const int t = threadIdx.x;
    const long base = (long)blockIdx.x * LCH;
    s[t] = dts[base + t];
    __syncthreads();
    for (int o = 1; o < LCH; o <<= 1) {
        float v = (t >= o) ? s[t - o] : 0.f;
        __syncthreads();
        s[t] += v;
        __syncthreads();
    }
    cumdt[base + t] = s[t];
}

// ---------------- phase A: chunk-local scan + fused conv4, per-wave staging (R14) ----------------
// Wave q owns states [32q,32q+32); stages its own sa/sb/sc slice (no barrier);
// yred parity-buffered -> 1 barrier per 8-row tile.  Inner loop in f32x2 packed
// ops (v_pk_fma_f32 / v_pk_mul_f32) to halve VALU issue count.
__global__ __launch_bounds__(256) void scan_local(const float* __restrict__ dts,
                                                  const float* __restrict__ bc,
                                                  const float* __restrict__ A_log,
                                                  const float* __restrict__ xm,
                                                  const float* __restrict__ cw,
                                                  const float* __restrict__ Dp,
                                                  bf16* __restrict__ ybuf,
                                                  float* __restrict__ hbuf) {
    const int tid = threadIdx.x;
    const int dl  = tid & 63;           // lane within wave = channel slot
    const int q   = tid >> 6;           // wave id = s-quarter
    const int d   = blockIdx.x * 64 + dl;
    const int ch  = blockIdx.y;
    const int b   = blockIdx.z;
    const long row0 = (long)b * TLEN + ch * LCH;
    const int s0   = q * 32;
    const int scol = dl & 31;
    const int half = dl >> 5;
    const float As_l = -expf(A_log[s0 + scol]);

    const float w0 = cw[d*4+0], w1 = cw[d*4+1], w2 = cw[d*4+2], w3 = cw[d*4+3];
    const float dpv = Dp[d];

    float p0 = 0.f, p1 = 0.f, p2 = 0.f;
    if (ch != 0) {
        p0 = csilu_fast(xm[(row0 - 3) * 2048 + d]);
        p1 = csilu_fast(xm[(row0 - 2) * 2048 + d]);
        p2 = csilu_fast(xm[(row0 - 1) * 2048 + d]);
    }

    f32x2 h2[16];
    #pragma unroll
    for (int k = 0; k < 16; ++k) h2[k] = (f32x2){0.f, 0.f};

    __shared__ __align__(16) float sa[8][128], sb[8][128], sc[8][128];   // 12 KB, wave-private slices
    __shared__ __align__(16) float yred[2][8][4][64];                    // 16 KB, parity-buffered
    int pbuf = 0;

    for (int tt = 0; tt < LCH; tt += 8) {
        // per-wave staging: lane covers rows {half, half+2, half+4, half+6}, col s0+scol
        #pragma unroll
        for (int k = 0; k < 4; ++k) {
            const int r = half + k*2;
            const long row = row0 + tt + r;
            const float dt = dts[row];
            const int sg = s0 + scol;
            sa[r][sg] = __expf(As_l * dt);
            sb[r][sg] = bc[row*256 + sg] * dt;       // B_bar
            sc[r][sg] = bc[row*256 + 128 + sg];      // raw C
        }
        #pragma unroll
        for (int r = 0; r < 8; ++r) {
            const long row = row0 + tt + r;
            const float cur = csilu_fast(xm[row * 2048 + d]);
            const float xc  = csilu_fast(w0*p0 + w1*p1 + w2*p2 + w3*cur);
            p0 = p1; p1 = p2; p2 = cur;
            const f32x2 xc2 = (f32x2){xc, xc};
            f32x2 yA = (f32x2){0.f, 0.f}, yB = (f32x2){0.f, 0.f};
            #pragma unroll
            for (int k = 0; k < 8; ++k) {            // 4 states per iter, as 2x f32x2
                const f32x4 a4 = *(const f32x4*)&sa[r][s0 + k*4];
                const f32x4 b4 = *(const f32x4*)&sb[r][s0 + k*4];
                const f32x4 c4 = *(const f32x4*)&sc[r][s0 + k*4];
                const f32x2 aL = {a4.x, a4.y}, aH = {a4.z, a4.w};
                const f32x2 bL = {b4.x, b4.y}, bH = {b4.z, b4.w};
                const f32x2 cL = {c4.x, c4.y}, cH = {c4.z, c4.w};
                h2[k*2+0] = aL * h2[k*2+0] + bL * xc2;   // v_pk_fma_f32 + v_pk_mul_f32
                h2[k*2+1] = aH * h2[k*2+1] + bH * xc2;
                yA = h2[k*2+0] * cL + yA;
                yB = h2[k*2+1] * cH + yB;
            }
            yred[pbuf][r][q][dl] = (yA.x + yA.y) + (yB.x + yB.y) + (q == 0 ? dpv * xc : 0.f);
        }
        __syncthreads();                         // all waves' yred[pbuf] writes visible
        #pragma unroll
        for (int i2 = 0; i2 < 2; ++i2) {
            const int i = tid + i2 * 256;
            const int r = i >> 6, dl2 = i & 63;
            const float y = yred[pbuf][r][0][dl2] + yred[pbuf][r][1][dl2]
                          + yred[pbuf][r][2][dl2] + yred[pbuf][r][3][dl2];
            ybuf[(row0 + tt + r) * 2048 + blockIdx.x * 64 + dl2] = __float2bfloat16(y);
        }
        pbuf ^= 1;                               // next tile writes other parity
    }
    // chunk-final h, transposed layout [d][s]: contiguous 32 floats per thread
    const long hb = ((long)(b * NCH + ch) * 2048 + d) * 128;
    #pragma unroll
    for (int k = 0; k < 8; ++k)
        *(float4*)&hbuf[hb + s0 + k*4] = make_float4(h2[k*2].x, h2[k*2].y, h2[k*2+1].x, h2[k*2+1].y);
}

// ---------------- phase B: cross-chunk combine; h_in -> hi/lo bf16 (transposed) + hT ----------------
__global__ __launch_bounds__(256) void scan_comb(const float* __restrict__ hbuf,
                                                 const float* __restrict__ cumdt,
                                                 const float* __restrict__ A_log,
                                                 bf16* __restrict__ hinH,
                                                 bf16* __restrict__ hinL,
                                                 float* __restrict__ hT) {
    const long idx = (long)blockIdx.x * 256 + threadIdx.x;   // over B*D*S, s fastest
    const int s = (int)(idx & 127);
    const int d = (int)((idx >> 7) & 2047);
    const int b = (int)(idx >> 18);
    const float As = -expf(A_log[s]);
    float hr = 0.f;
    for (int c = 0; c < NCH; ++c) {
        const long off = ((long)(b * NCH + c) * 2048 + d) * 128 + s;
        const float loc = hbuf[off];
        const bf16 hh = __float2bfloat16(hr);
        hinH[off] = hh;
        hinL[off] = __float2bfloat16(hr - __bfloat162float(hh));
        const float p = __expf(As * cumdt[(long)b * TLEN + c * LCH + (LCH - 1)]);
        hr = p * hr + loc;
    }
    hT[((long)b * 2048 + d) * 128 + s] = hr;
}

// ---------------- phase C as GEMM: Y += Cmod(512x128) @ Hin(128x2048) per (b,ch) ----------------
__global__ __launch_bounds__(256) void corr_gemm(const float* __restrict__ cumdt,
                                                 const float* __restrict__ bc,
                                                 const float* __restrict__ A_log,
                                                 const bf16* __restrict__ hinH,
                                                 const bf16* __restrict__ hinL,
                                                 bf16* __restrict__ ybuf) {
    __shared__ __align__(16) bf16 sA[128*32];
    __shared__ __align__(16) bf16 sBh[128*32], sBl[128*32];
    const int tid  = threadIdx.x;
    const int lane = tid & 63;
    const int wave = tid >> 6;
    const int wr   = (wave >> 1) * 64;
    const int wc   = (wave & 1) * 64;
    const long arow0 = (long)blockIdx.x * 128;      // rows over BT (within one 512-chunk)
    const long bcol0 = (long)blockIdx.y * 128;      // channels
    const int b  = (int)(arow0 >> 12);
    const int ch = (int)((arow0 & 4095) >> 9);
    const char* gH = (const char*)(hinH + (long)(b * NCH + ch) * 2048 * 128);
    const char* gL = (const char*)(hinL + (long)(b * NCH + ch) * 2048 * 128);

    f32x4 acc[4][4] = {};
    const int c1 = tid, c2 = tid + 256;
    for (int k0 = 0; k0 < 128; k0 += 32) {
        __syncthreads();
        {
            const int r   = tid >> 1;
            const int kk0 = (tid & 1) * 16;
            const long row = arow0 + r;
            const float cd = cumdt[row];
            #pragma unroll
            for (int t2 = 0; t2 < 16; ++t2) {
                const int s = k0 + kk0 + t2;
                const float As = -__expf(A_log[s]);
                const float cm = bc[row*256 + 128 + s] * __expf(As * cd);
                sA[r*32 + kk0 + t2] = __float2bfloat16(cm);
            }
        }
        gload_lds16(gH + (bcol0 + (c1 >> 2))*256 + k0*2 + (c1 & 3)*16, (char*)sBh + c1*16);
        gload_lds16(gH + (bcol0 + (c2 >> 2))*256 + k0*2 + (c2 & 3)*16, (char*)sBh + c2*16);
        gload_lds16(gL + (bcol0 + (c1 >> 2))*256 + k0*2 + (c1 & 3)*16, (char*)sBl + c1*16);
        gload_lds16(gL + (bcol0 + (c2 >> 2))*256 + k0*2 + (c2 & 3)*16, (char*)sBl + c2*16);
        __syncthreads();

        const int r    = lane & 15;
        const int koff = (lane >> 4) * 8;
        short8x af[4], bh[4], bl[4];
        #pragma unroll
        for (int m = 0; m < 4; ++m)
            af[m] = *(const short8x*)(sA + (wr + m*16 + r) * 32 + koff);
        #pragma unroll
        for (int n = 0; n < 4; ++n) {
            bh[n] = *(const short8x*)(sBh + (wc + n*16 + r) * 32 + koff);
            bl[n] = *(const short8x*)(sBl + (wc + n*16 + r) * 32 + koff);
        }
        #pragma unroll
        for (int m = 0; m < 4; ++m)
            #pragma unroll
            for (int n = 0; n < 4; ++n) {
                acc[m][n] = __builtin_amdgcn_mfma_f32_16x16x32_bf16(af[m], bh[n], acc[m][n], 0, 0, 0);
                acc[m][n] = __builtin_amdgcn_mfma_f32_16x16x32_bf16(af[m], bl[n], acc[m][n], 0, 0, 0);
            }
    }

    const int r4 = (lane >> 4) * 4;
    const int cl = lane & 15;
    #pragma unroll
    for (int m = 0; m < 4; ++m) {
        #pragma unroll
        for (int n = 0; n < 4; ++n) {
            const long row = arow0 + wr + m*16 + r4;
            const long col = bcol0 + wc + n*16 + cl;
            #pragma unroll
            for (int j = 0; j < 4; ++j) {
                const long o = (row + j) * 2048 + col;
                ybuf[o] = __float2bfloat16(__bfloat162float(ybuf[o]) + acc[m][n][j]);
            }
        }
    }
}

// ---------------- RMSNorm * norm_w * csilu(z): ygated bf16 written over z ----------------
__global__ __launch_bounds__(256) void rms_z(const bf16* __restrict__ ybuf,
                                             bf16* __restrict__ zg,
                                             const float* __restrict__ norm_w) {
    const long row = blockIdx.x;
    const int tid = threadIdx.x;
    float v[8];
    float ss = 0.f;
    #pragma unroll
    for (int i = 0; i < 8; ++i) {
        v[i] = __bfloat162float(ybuf[row * D_INNER + i*256 + tid]);
        ss += v[i] * v[i];
    }
    __shared__ float red[256];
    red[tid] = ss;
    __syncthreads();
    for (int o = 128; o > 0; o >>= 1) {
        if (tid < o) red[tid] += red[tid + o];
        __syncthreads();
    }
    const float scale = rsqrtf(red[0] * (1.f / D_INNER) + 1e-5f);
    #pragma unroll
    for (int i = 0; i < 8; ++i) {
        const int dd = i*256 + tid;
        const float z = __bfloat162float(zg[row * D_INNER + dd]);
        zg[row * D_INNER + dd] = __float2bfloat16(v[i] * scale * norm_w[dd] * csilu_fast(z));
    }
}

extern "C" void kernel_launch(void* const* d_in, const int* in_sizes, int n_in,
                              void* d_out, int out_size, void* d_ws, size_t ws_size,
                              hipStream_t stream) {
    const float* x      = (const float*)d_in[0];
    const float* in_w   = (const float*)d_in[1];   // (4353, 1024)
    const float* conv_w = (const float*)d_in[2];   // (2048, 1, 4)
    const float* A_log  = (const float*)d_in[3];   // (128,)
    const float* Dp     = (const float*)d_in[4];   // (2048,)
    const float* norm_w = (const float*)d_in[5];   // (2048,)
    const float* out_w  = (const float*)d_in[6];   // (1024, 2048)
    float* out = (float*)d_out;
    float* hT  = out + (long)BT * D_MODEL;

    char* ws = (char*)d_ws;
    size_t off = 0;
    auto alloc = [&](size_t bytes) { void* p = ws + off; off += (bytes + 255) & ~(size_t)255; return p; };
    bf16*  zg    = (bf16*) alloc((size_t)BT * D_INNER * 2);               //  67.1 MB: z -> ygated
    float* xm    = (float*)alloc((size_t)BT * D_INNER * 4);               // 134.2 MB: xm f32
    float* bcbuf = (float*)alloc((size_t)BT * 256 * 4);                   //  16.8 MB: B|C f32
    bf16*  w2b   = (bf16*) alloc((size_t)D_MODEL * D_INNER * 2);          //   4.2 MB
    float* hbuf  = (float*)alloc((size_t)NB * NCH * 128 * D_INNER * 4);   //  33.5 MB
    float* dts   = (float*)alloc((size_t)BT * 4);
    float* cumdt = (float*)alloc((size_t)BT * 4);
    // total ~256.0 MB (PROVEN).  Guarded.
    if (ws_size < off) return;

    // Aliases (lifetime-disjoint):
    bf16* whi = (bf16*)hbuf;                      // [split_w -> gemm1]; hbuf written by scan_local
    bf16* wlo = whi + (size_t)NCOLS * D_MODEL;
    bf16* xhi = (bf16*)d_out;                     // [split_x -> gemm1]
    bf16* xlo = xhi + (size_t)BT * D_MODEL;
    bf16* ybuf = (bf16*)d_out;                    // [scan_local -> rms_z], then gemm2 writes out
    bf16* hinH = (bf16*)xm;                       // [comb -> corr]; xm dead after scan_local
    bf16* hinL = hinH + (size_t)NB * NCH * D_INNER * 128;

    split_kernel<<<BT*D_MODEL/4/256, 256, 0, stream>>>(x, xhi, xlo, BT*D_MODEL/4);
    split_kernel<<<NCOLS*D_MODEL/4/256, 256, 0, stream>>>(in_w, whi, wlo, NCOLS*D_MODEL/4);
    cast_kernel<<<D_MODEL*D_INNER/4/256, 256, 0, stream>>>(out_w, w2b, D_MODEL*D_INNER/4);

    gemm1_split<<<dim3(BT/128, NCOLS/128), 256, 0, stream>>>(xhi, xlo, whi, wlo, zg, xm, bcbuf);
    dt_gemv<<<BT/4, 256, 0, stream>>>(x, in_w + (long)NCOLS * D_MODEL, dts);
    cumsum_chunks<<<NB*NCH, LCH, 0, stream>>>(dts, cumdt);
    scan_local<<<dim3(D_INNER/64, NCH, NB), 256, 0, stream>>>(dts, bcbuf, A_log, xm, conv_w, Dp, ybuf, hbuf);
    scan_comb<<<NB*128*D_INNER/256, 256, 0, stream>>>(hbuf, cumdt, A_log, hinH, hinL, hT);
    corr_gemm<<<dim3(BT/128, D_INNER/128), 256, 0, stream>>>(cumdt, bcbuf, A_log, hinH, hinL, ybuf);
    rms_z<<<BT, 256, 0, stream>>>(ybuf, zg, norm_w);
    gemm2_mfma<<<dim3(BT/128, D_MODEL/128), 256, 0, stream>>>(zg, w2b, out);
}